// Round 13
// baseline (443.920 us; speedup 1.0000x reference)
//
#include <hip/hip_runtime.h>

// ---------------------------------------------------------------------------
// GCN model, re-associated: per layer h = relu((A_hat @ h_prev) @ W^T + b);
// pool BEFORE gcn_out linear. Node features BF16 (fp32 accumulate), dinv
// folded into features. CSR via single-pass padded-region binning with
// line-padded cursors. Head: wave-per-output-neuron — weight rows read fully
// coalesced (64 lanes x 16B = one row), acts in registers, shfl reduce.
// ---------------------------------------------------------------------------

typedef __attribute__((ext_vector_type(8))) short short8;   // MFMA A/B frag
typedef __attribute__((ext_vector_type(4))) float f32x4;    // MFMA C/D frag

#define BKT 64        // nodes per bucket
#define SL 16         // slices per bucket
#define CAP 192       // capacity per (bucket,slice) cell   (Poisson 64)
#define WCAP 2560     // csrf window per bucket             (Poisson 1024)
#define NBINBLK 2048  // k_bin grid
#define HROWS 65536   // h-buffer rows allocated (16-bit src ids -> safe)

__device__ __forceinline__ unsigned short f2bf(float f) {
    union { float f; unsigned u; } c; c.f = f;
    unsigned u = c.u;
    unsigned r = u + 0x7FFFu + ((u >> 16) & 1u);   // RNE
    return (unsigned short)(r >> 16);
}
__device__ __forceinline__ float bflo(unsigned w) {
    union { unsigned u; float f; } c; c.u = w << 16; return c.f;
}
__device__ __forceinline__ float bfhi(unsigned w) {
    union { unsigned u; float f; } c; c.u = w & 0xFFFF0000u; return c.f;
}
__device__ __forceinline__ float wred(float v) {
    #pragma unroll
    for (int off = 32; off; off >>= 1) v += __shfl_xor(v, off, 64);
    return v;
}

// zero line-padded cursors (16 ints apart), pool/cnt; cast gcn_W -> bf16
// pre-swizzled for k_mm's LDS layout. Grid must cover M*16 threads.
__global__ void k_init(int* cur, float* pool, float* cnt,
                       const float* __restrict__ gcnW, uint4* __restrict__ Wb,
                       int M, int G) {
    int i = blockIdx.x * 256 + threadIdx.x;
    if (i < M * 16) cur[i] = 0;
    if (i < G * 128) pool[i] = 0.f;
    if (i < G) cnt[i] = 0.f;
    if (i < 3 * 2048) {                  // W cast: chunk c=k/8 of row o, layer l
        int l = i >> 11, rem = i & 2047;
        int o = rem >> 4, c = rem & 15;
        const float4* s = (const float4*)(gcnW + (size_t)l * 16384 + o * 128 + c * 8);
        float4 a = s[0], b = s[1];
        uint4 v;
        v.x = ((unsigned)f2bf(a.y) << 16) | f2bf(a.x);
        v.y = ((unsigned)f2bf(a.w) << 16) | f2bf(a.z);
        v.z = ((unsigned)f2bf(b.y) << 16) | f2bf(b.x);
        v.w = ((unsigned)f2bf(b.w) << 16) | f2bf(b.z);
        Wb[(l << 11) | (o << 4) | (c ^ (o & 15))] = v;
    }
}

// Single-pass binning. Cursor cell = cur[cell*16] (one 64B line per cell);
// gbin position = cell*CAP + count (closed form).
__global__ __launch_bounds__(256) void k_bin(const int* __restrict__ row,
                                             const int* __restrict__ col,
                                             int* __restrict__ cur,
                                             unsigned* __restrict__ gbin,
                                             int E, int C) {
    const int x = blockIdx.x & (SL - 1);
    int e0 = blockIdx.x * C, e1 = min(E, e0 + C);
    for (int e = e0 + threadIdx.x; e < e1; e += 256) {
        int c = col[e];
        int cell = (c >> 6) * SL + x;
        int cnt = atomicAdd(&cur[cell << 4], 1);
        gbin[cell * CAP + cnt] = (unsigned)row[e] | ((unsigned)(c & 63) << 16);
    }
}

// One block per bucket: LDS histogram of 64 dsts -> (start,deg,dinv), scatter
// 2B src ids into the bucket's padded csrf window, fused x->bf16*dinv cast.
__global__ __launch_bounds__(256) void k_csr(const unsigned* __restrict__ gbin,
                                             const int* __restrict__ cur,
                                             int* __restrict__ rs,
                                             unsigned short* __restrict__ rd,
                                             float* __restrict__ dinv,
                                             unsigned short* __restrict__ csrf,
                                             const float* __restrict__ x,
                                             unsigned short* __restrict__ xb,
                                             int N) {
    const int b = blockIdx.x, t = threadIdx.x;
    __shared__ int hcnt[64], lcur[64], fills[SL];
    __shared__ float sdinv[64];
    if (t < 64) hcnt[t] = 0;
    if (t < SL) fills[t] = cur[(b * SL + t) << 4];
    __syncthreads();
    #pragma unroll 4
    for (int xx = 0; xx < SL; ++xx) {
        int cbase = (b * SL + xx) * CAP, fill = fills[xx];
        for (int i = t; i < fill; i += 256)
            atomicAdd(&hcnt[(gbin[cbase + i] >> 16) & 63], 1);
    }
    __syncthreads();
    if (t < 64) {
        int v = hcnt[t], xs = v;
        #pragma unroll
        for (int off = 1; off < 64; off <<= 1) {
            int u = __shfl_up(xs, off, 64);
            if (t >= off) xs += u;
        }
        int excl = xs - v;
        lcur[t] = excl;
        float d = rsqrtf((float)v + 1.0f);
        sdinv[t] = d;
        int node = b * 64 + t;          // rs/rd/dinv sized NBK*64: always safe
        rs[node] = b * WCAP + excl;
        rd[node] = (unsigned short)v;
        dinv[node] = d;
    }
    __syncthreads();
    #pragma unroll 4
    for (int xx = 0; xx < SL; ++xx) {
        int cbase = (b * SL + xx) * CAP, fill = fills[xx];
        for (int i = t; i < fill; i += 256) {
            unsigned v = gbin[cbase + i];
            int p = atomicAdd(&lcur[(v >> 16) & 63], 1);
            csrf[b * WCAP + p] = (unsigned short)(v & 0xFFFFu);
        }
    }
    // fused x -> bf16*dinv cast (64 nodes x 16 chunks)
    const int node0 = b * 64;
    #pragma unroll
    for (int it = 0; it < 4; ++it) {
        int i = t + it * 256;              // 0..1023
        int nd = node0 + (i >> 4);
        if (nd < N) {
            int ch = i & 15;
            float d = sdinv[i >> 4];
            const float4* s = (const float4*)(x + (size_t)nd * 128 + ch * 8);
            float4 a = s[0], bb = s[1];
            uint4 o;
            o.x = ((unsigned)f2bf(d * a.y) << 16) | f2bf(d * a.x);
            o.y = ((unsigned)f2bf(d * a.w) << 16) | f2bf(d * a.z);
            o.z = ((unsigned)f2bf(d * bb.y) << 16) | f2bf(d * bb.x);
            o.w = ((unsigned)f2bf(d * bb.w) << 16) | f2bf(d * bb.z);
            *(uint4*)(xb + (size_t)nd * 128 + ch * 8) = o;
        }
    }
}

// y[n] = dinv[n] * (sum_src h'[src] + h'[n])   (h', y bf16)
// One wave per node, 4/block: max latency-hiding parallelism for the gather.
__global__ __launch_bounds__(256) void k_agg(const unsigned short* __restrict__ h,
                                             unsigned short* __restrict__ y,
                                             const float* __restrict__ dinv,
                                             const int* __restrict__ rs,
                                             const unsigned short* __restrict__ rd,
                                             const unsigned short* __restrict__ csrf,
                                             int N) {
    const int lane = threadIdx.x & 63;
    const int n = blockIdx.x * 4 + (threadIdx.x >> 6);
    if (n >= N) return;
    const int fg = lane & 15;
    const int slot = lane >> 4;
    const int s = rs[n], e = s + rd[n];

    float acc[8] = {0.f, 0.f, 0.f, 0.f, 0.f, 0.f, 0.f, 0.f};
    for (int base = s; base < e; base += 16) {
        int src_l = csrf[base + fg];               // padded window: in-bounds
        #pragma unroll
        for (int i = 0; i < 4; ++i) {
            int j = i * 4 + slot;
            int src = __shfl(src_l, j, 16);
            uint4 v = *(const uint4*)(h + (size_t)src * 128 + fg * 8);
            bool ok = (base + j) < e;              // mask value, not address
            v.x = ok ? v.x : 0u; v.y = ok ? v.y : 0u;
            v.z = ok ? v.z : 0u; v.w = ok ? v.w : 0u;
            acc[0] += bflo(v.x); acc[1] += bfhi(v.x);
            acc[2] += bflo(v.y); acc[3] += bfhi(v.y);
            acc[4] += bflo(v.z); acc[5] += bfhi(v.z);
            acc[6] += bflo(v.w); acc[7] += bfhi(v.w);
        }
    }
    #pragma unroll
    for (int r = 0; r < 8; ++r) {
        acc[r] += __shfl_xor(acc[r], 16, 64);
        acc[r] += __shfl_xor(acc[r], 32, 64);
    }
    if (slot == 0) {
        float dn = dinv[n];
        uint4 hv = *(const uint4*)(h + (size_t)n * 128 + fg * 8);
        float sv[8] = {bflo(hv.x), bfhi(hv.x), bflo(hv.y), bfhi(hv.y),
                       bflo(hv.z), bfhi(hv.z), bflo(hv.w), bfhi(hv.w)};
        unsigned short ob[8];
        #pragma unroll
        for (int r = 0; r < 8; ++r) ob[r] = f2bf(dn * (acc[r] + sv[r]));
        uint4 o;
        o.x = ((unsigned)ob[1] << 16) | ob[0];
        o.y = ((unsigned)ob[3] << 16) | ob[2];
        o.z = ((unsigned)ob[5] << 16) | ob[4];
        o.w = ((unsigned)ob[7] << 16) | ob[6];
        *(uint4*)(y + (size_t)n * 128 + fg * 8) = o;
    }
}

// C[N,128] = relu(A @ W^T + b) [* dscale[row] if dscale] in bf16 via MFMA.
__global__ __launch_bounds__(256) void k_mm(const unsigned short* __restrict__ A,
                                            const uint4* __restrict__ Wb,
                                            const float* __restrict__ bias,
                                            const float* __restrict__ dscale,
                                            unsigned short* __restrict__ C, int N) {
    __shared__ uint4 Wsh[2048];   // 32 KB, swizzled [o][c^(o&15)]
    const int tid = threadIdx.x;
    #pragma unroll
    for (int it = 0; it < 8; ++it)
        Wsh[tid + it * 256] = Wb[tid + it * 256];

    const int lane = tid & 63;
    const int wv = tid >> 6;
    const int l15 = lane & 15, quad = lane >> 4;
    const int arow_i = blockIdx.x * 64 + wv * 16 + l15;
    const unsigned short* arow = A + (size_t)min(arow_i, N - 1) * 128;

    f32x4 acc[8];
    #pragma unroll
    for (int ct = 0; ct < 8; ++ct) acc[ct] = (f32x4){0.f, 0.f, 0.f, 0.f};

    __syncthreads();
    #pragma unroll
    for (int kiter = 0; kiter < 4; ++kiter) {
        short8 af = *(const short8*)(arow + kiter * 32 + quad * 8);
        const int cswz = (kiter * 4 + quad) ^ l15;
        #pragma unroll
        for (int ct = 0; ct < 8; ++ct) {
            short8 bf = *(const short8*)(&Wsh[((ct * 16 + l15) << 4) | cswz]);
            acc[ct] = __builtin_amdgcn_mfma_f32_16x16x32_bf16(af, bf, acc[ct], 0, 0, 0);
        }
    }

    const int rbase = blockIdx.x * 64 + wv * 16 + quad * 4;
    float ds[4];
    #pragma unroll
    for (int r = 0; r < 4; ++r) {
        int rr = rbase + r;
        ds[r] = (dscale && rr < N) ? dscale[rr] : 1.f;
    }
    #pragma unroll
    for (int ct = 0; ct < 8; ++ct) {
        int colc = ct * 16 + l15;
        float bcol = bias[colc];
        #pragma unroll
        for (int r = 0; r < 4; ++r) {
            int rr = rbase + r;
            if (rr < N) {
                float v = fmaxf(acc[ct][r] + bcol, 0.f) * ds[r];
                C[(size_t)rr * 128 + colc] = f2bf(v);
            }
        }
    }
}

// Mean-pool accumulate (batch sorted), bf16 input, fp32 atomics out.
__global__ __launch_bounds__(256) void k_pool(const unsigned short* __restrict__ h,
                                              const int* __restrict__ batch,
                                              float* __restrict__ pool,
                                              float* __restrict__ cnt, int N) {
    int t = threadIdx.x;
    int fg = t & 15, sg = t >> 4;
    int n0 = blockIdx.x * 512 + sg * 32;
    if (n0 >= N) return;
    int n1 = min(n0 + 32, N);
    int gprev = batch[n0];
    float racc[8] = {0.f, 0.f, 0.f, 0.f, 0.f, 0.f, 0.f, 0.f};
    float rcnt = 0.f;
    for (int n = n0; n < n1; ++n) {
        int g = batch[n];
        if (g != gprev) {
            float* dst = pool + (size_t)gprev * 128 + fg * 8;
            #pragma unroll
            for (int r = 0; r < 8; ++r) atomicAdd(dst + r, racc[r]);
            if (fg == 0) atomicAdd(&cnt[gprev], rcnt);
            #pragma unroll
            for (int r = 0; r < 8; ++r) racc[r] = 0.f;
            rcnt = 0.f; gprev = g;
        }
        uint4 v = *(const uint4*)(h + (size_t)n * 128 + fg * 8);
        racc[0] += bflo(v.x); racc[1] += bfhi(v.x);
        racc[2] += bflo(v.y); racc[3] += bfhi(v.y);
        racc[4] += bflo(v.z); racc[5] += bfhi(v.z);
        racc[6] += bflo(v.w); racc[7] += bfhi(v.w);
        rcnt += 1.f;
    }
    float* dst = pool + (size_t)gprev * 128 + fg * 8;
    #pragma unroll
    for (int r = 0; r < 8; ++r) atomicAdd(dst + r, racc[r]);
    if (fg == 0) atomicAdd(&cnt[gprev], rcnt);
}

// Fused head: 1 graph/block, 256 threads = 4 waves. Wave-per-output-neuron:
// 64 lanes read one weight row coalesced (lane k4 = lane, 16B each -> 1 KB),
// acts in registers (loaded once/layer), 6-step shfl_xor reduce. Output
// iterations independent -> unroll keeps 8 row-loads in flight.
__global__ __launch_bounds__(256) void k_head(
    const float* __restrict__ pool, const float* __restrict__ cnt,
    const float* __restrict__ gcnoW, const float* __restrict__ gcnob,
    const float* __restrict__ mol,
    const float* __restrict__ mlpW, const float* __restrict__ mlpb,
    const float* __restrict__ mloW, const float* __restrict__ mlob,
    const float* __restrict__ pW1, const float* __restrict__ pb1,
    const float* __restrict__ pW2, const float* __restrict__ pb2,
    const float* __restrict__ oW, const float* __restrict__ ob,
    float* __restrict__ out, int G) {
    const int g = blockIdx.x;
    const int t = threadIdx.x;
    const int lane = t & 63, wv = t >> 6;
    __shared__ float A[256], B[256], Cc[192], Mn[128];
    __shared__ float red[4];

    A[t] = mol[(size_t)g * 256 + t];
    if (t < 128) {
        float c = cnt[g];
        Mn[t] = pool[(size_t)g * 128 + t] / fmaxf(c, 1.f);
    }
    __syncthreads();

    // mlp0: A(K=256) -> B, relu
    {
        float4 s = *(const float4*)(&A[lane * 4]);
        #pragma unroll 8
        for (int i = 0; i < 64; ++i) {
            int o = wv * 64 + i;
            float4 w = *(const float4*)(mlpW + (size_t)o * 256 + lane * 4);
            float v = wred(w.x * s.x + w.y * s.y + w.z * s.z + w.w * s.w);
            if (lane == 0) B[o] = fmaxf(v + mlpb[o], 0.f);
        }
    }
    __syncthreads();

    // mlp1: B(K=256) -> A, relu
    {
        float4 s = *(const float4*)(&B[lane * 4]);
        #pragma unroll 8
        for (int i = 0; i < 64; ++i) {
            int o = wv * 64 + i;
            float4 w = *(const float4*)(mlpW + 65536 + (size_t)o * 256 + lane * 4);
            float v = wred(w.x * s.x + w.y * s.y + w.z * s.z + w.w * s.w);
            if (lane == 0) A[o] = fmaxf(v + mlpb[256 + o], 0.f);
        }
    }
    __syncthreads();

    // concat (192 outputs, 48/wave): co<128 -> gcn_out row co (K=128 from Mn,
    // no relu); co>=128 -> mlo row co-128 (K=256 from A, relu)
    {
        float4 sa = *(const float4*)(&A[lane * 4]);
        float mmask = (lane < 32) ? 1.f : 0.f;
        float4 sm = *(const float4*)(&Mn[(lane & 31) * 4]);
        #pragma unroll 4
        for (int i = 0; i < 48; ++i) {
            int co = wv * 48 + i;
            float v;
            if (co < 128) {
                float4 w = *(const float4*)(gcnoW + (size_t)co * 128 + (lane & 31) * 4);
                v = wred(mmask * (w.x * sm.x + w.y * sm.y + w.z * sm.z + w.w * sm.w));
                if (lane == 0) Cc[co] = v + gcnob[co];
            } else {
                int o = co - 128;
                float4 w = *(const float4*)(mloW + (size_t)o * 256 + lane * 4);
                v = wred(w.x * sa.x + w.y * sa.y + w.z * sa.z + w.w * sa.w);
                if (lane == 0) Cc[co] = fmaxf(v + mlob[o], 0.f);
            }
        }
    }
    __syncthreads();

    // pred1: Cc(K=192) -> B, relu (lanes 48..63 masked)
    {
        float pmask = (lane < 48) ? 1.f : 0.f;
        int koff = min(lane * 4, 188);
        float4 s = *(const float4*)(&Cc[koff & ~3]);
        #pragma unroll 8
        for (int i = 0; i < 64; ++i) {
            int o = wv * 64 + i;
            float4 w = *(const float4*)(pW1 + (size_t)o * 192 + min(lane * 4, 188));
            float v = wred(pmask * (w.x * s.x + w.y * s.y + w.z * s.z + w.w * s.w));
            if (lane == 0) B[o] = fmaxf(v + pb1[o], 0.f);
        }
    }
    __syncthreads();

    // pred2 (K=256) fused with out-dot: never materialize pred2 outputs
    {
        float4 s = *(const float4*)(&B[lane * 4]);
        float dacc = 0.f;
        #pragma unroll 8
        for (int i = 0; i < 64; ++i) {
            int o = wv * 64 + i;
            float4 w = *(const float4*)(pW2 + (size_t)o * 256 + lane * 4);
            float v = wred(w.x * s.x + w.y * s.y + w.z * s.z + w.w * s.w);
            dacc += fmaxf(v + pb2[o], 0.f) * oW[o];   // wave-uniform after wred
        }
        if (lane == 0) red[wv] = dacc;
    }
    __syncthreads();
    if (t == 0) out[g] = red[0] + red[1] + red[2] + red[3] + ob[0];
}

extern "C" void kernel_launch(void* const* d_in, const int* in_sizes, int n_in,
                              void* d_out, int out_size, void* d_ws, size_t ws_size,
                              hipStream_t stream) {
    const float* x     = (const float*)d_in[0];
    const int*   ei    = (const int*)d_in[1];
    const int*   batch = (const int*)d_in[2];
    const float* mol   = (const float*)d_in[3];
    const float* gcnW  = (const float*)d_in[4];
    const float* gcnb  = (const float*)d_in[5];
    const float* gcnoW = (const float*)d_in[6];
    const float* gcnob = (const float*)d_in[7];
    const float* mlpW  = (const float*)d_in[8];
    const float* mlpb  = (const float*)d_in[9];
    const float* mloW  = (const float*)d_in[10];
    const float* mlob  = (const float*)d_in[11];
    const float* pW1   = (const float*)d_in[12];
    const float* pb1   = (const float*)d_in[13];
    const float* pW2   = (const float*)d_in[14];
    const float* pb2   = (const float*)d_in[15];
    const float* oW    = (const float*)d_in[16];
    const float* ob    = (const float*)d_in[17];

    const int N = in_sizes[0] / 128;
    const int E = in_sizes[1] / 2;
    const int G = in_sizes[3] / 256;
    const int* row = ei;
    const int* col = ei + E;

    const int NBK = (N + BKT - 1) / BKT;       // 782 buckets
    const int M = NBK * SL;                    // 12512 cells
    const int C = (E + NBINBLK - 1) / NBINBLK; // edges per bin block

    char* p = (char*)d_ws;
    auto alloc = [&](size_t bytes) {
        char* q = p;
        p += (bytes + 255) & ~(size_t)255;
        return (void*)q;
    };
    int*    rs    = (int*)alloc((size_t)NBK * 64 * 4);
    unsigned short* rd = (unsigned short*)alloc((size_t)NBK * 64 * 2);
    float*  dinv  = (float*)alloc((size_t)NBK * 64 * 4);
    int*    cur   = (int*)alloc((size_t)M * 16 * 4);   // line-padded cursors
    unsigned* gbin = (unsigned*)alloc((size_t)M * CAP * 4);
    unsigned short* csrf = (unsigned short*)alloc(((size_t)NBK * WCAP + 32) * 2);
    unsigned short* xb   = (unsigned short*)alloc((size_t)HROWS * 128 * 2);
    unsigned short* bufA = (unsigned short*)alloc((size_t)HROWS * 128 * 2);
    unsigned short* bufB = (unsigned short*)alloc((size_t)HROWS * 128 * 2);
    uint4*  Wb    = (uint4*)alloc((size_t)3 * 2048 * 16);
    float*  pool  = (float*)alloc((size_t)G * 128 * 4);
    float*  cnt   = (float*)alloc((size_t)G * 4);

    const int initblocks = (M * 16 + 255) / 256;   // covers cursor zeroing

    k_init<<<initblocks, 256, 0, stream>>>(cur, pool, cnt, gcnW, Wb, M, G);
    k_bin<<<NBINBLK, 256, 0, stream>>>(row, col, cur, gbin, E, C);
    k_csr<<<NBK, 256, 0, stream>>>(gbin, cur, rs, rd, dinv, csrf, x, xb, N);

    const int mmblocks = (N + 63) / 64;
    const int aggblocks = (N + 3) / 4;
    const unsigned short* src = xb;
    for (int l = 0; l < 3; ++l) {
        k_agg<<<aggblocks, 256, 0, stream>>>(src, bufA, dinv, rs, rd, csrf, N);
        k_mm<<<mmblocks, 256, 0, stream>>>(bufA, Wb + (size_t)l * 2048,
                                           gcnb + (size_t)l * 128,
                                           (l < 2) ? dinv : (const float*)nullptr,
                                           bufB, N);
        src = bufB;
    }
    k_pool<<<(N + 511) / 512, 256, 0, stream>>>(bufB, batch, pool, cnt, N);
    k_head<<<G, 256, 0, stream>>>(pool, cnt, gcnoW, gcnob, mol, mlpW, mlpb,
                                  mloW, mlob, pW1, pb1, pW2, pb2, oW, ob,
                                  (float*)d_out, G);
}

// Round 14
// 349.372 us; speedup vs baseline: 1.2706x; 1.2706x over previous
//
#include <hip/hip_runtime.h>

// ---------------------------------------------------------------------------
// GCN model, re-associated: per layer h = relu((A_hat @ h_prev) @ W^T + b);
// pool BEFORE gcn_out linear. Node features BF16 (fp32 accumulate), dinv
// folded into features. CSR via single-pass padded-region binning with
// line-padded cursors. Head: batched MFMA GEMM — 16 graphs/block, bf16
// weights pre-cast, activations in LDS, fp32 accumulation.
// ---------------------------------------------------------------------------

typedef __attribute__((ext_vector_type(8))) short short8;   // MFMA A/B frag
typedef __attribute__((ext_vector_type(4))) float f32x4;    // MFMA C/D frag

#define BKT 64        // nodes per bucket
#define SL 16         // slices per bucket
#define CAP 192       // capacity per (bucket,slice) cell   (Poisson 64)
#define WCAP 2560     // csrf window per bucket             (Poisson 1024)
#define NBINBLK 2048  // k_bin grid
#define HROWS 65536   // h-buffer rows allocated (16-bit src ids -> safe)

// Head-weight bf16 arena offsets (elements)
#define HW_MLP0 0
#define HW_MLP1 65536
#define HW_MLO  131072
#define HW_GCNO 147456
#define HW_PW1  163840
#define HW_PW2  212992
#define HW_TOT  278528

__device__ __forceinline__ unsigned short f2bf(float f) {
    union { float f; unsigned u; } c; c.f = f;
    unsigned u = c.u;
    unsigned r = u + 0x7FFFu + ((u >> 16) & 1u);   // RNE
    return (unsigned short)(r >> 16);
}
__device__ __forceinline__ float bflo(unsigned w) {
    union { unsigned u; float f; } c; c.u = w << 16; return c.f;
}
__device__ __forceinline__ float bfhi(unsigned w) {
    union { unsigned u; float f; } c; c.u = w & 0xFFFF0000u; return c.f;
}

// zero line-padded cursors, pool/cnt; cast gcn_W -> swizzled bf16 (k_mm);
// cast ALL head weights -> flat bf16 arena Wh (k_head MFMA B-frags).
__global__ void k_init(int* cur, float* pool, float* cnt,
                       const float* __restrict__ gcnW, uint4* __restrict__ Wb,
                       const float* __restrict__ mlpW, const float* __restrict__ mloW,
                       const float* __restrict__ gcnoW, const float* __restrict__ pW1,
                       const float* __restrict__ pW2, unsigned short* __restrict__ Wh,
                       int M, int G) {
    int i = blockIdx.x * 256 + threadIdx.x;
    if (i < M * 16) cur[i] = 0;
    if (i < G * 128) pool[i] = 0.f;
    if (i < G) cnt[i] = 0.f;
    if (i < 3 * 2048) {                  // gcn W cast: chunk c=k/8, row o, layer l
        int l = i >> 11, rem = i & 2047;
        int o = rem >> 4, c = rem & 15;
        const float4* s = (const float4*)(gcnW + (size_t)l * 16384 + o * 128 + c * 8);
        float4 a = s[0], b = s[1];
        uint4 v;
        v.x = ((unsigned)f2bf(a.y) << 16) | f2bf(a.x);
        v.y = ((unsigned)f2bf(a.w) << 16) | f2bf(a.z);
        v.z = ((unsigned)f2bf(b.y) << 16) | f2bf(b.x);
        v.w = ((unsigned)f2bf(b.w) << 16) | f2bf(b.z);
        Wb[(l << 11) | (o << 4) | (c ^ (o & 15))] = v;
    }
    int j = i - 8192;                    // head-weight flat cast, 8 elems/thread
    if (j >= 0 && j < (HW_TOT / 8)) {
        int e = j * 8;
        const float* src;
        if (e < HW_MLO)        src = mlpW  + e;
        else if (e < HW_GCNO)  src = mloW  + (e - HW_MLO);
        else if (e < HW_PW1)   src = gcnoW + (e - HW_GCNO);
        else if (e < HW_PW2)   src = pW1   + (e - HW_PW1);
        else                   src = pW2   + (e - HW_PW2);
        float4 a = *(const float4*)src;
        float4 b = *((const float4*)src + 1);
        uint4 v;
        v.x = ((unsigned)f2bf(a.y) << 16) | f2bf(a.x);
        v.y = ((unsigned)f2bf(a.w) << 16) | f2bf(a.z);
        v.z = ((unsigned)f2bf(b.y) << 16) | f2bf(b.x);
        v.w = ((unsigned)f2bf(b.w) << 16) | f2bf(b.z);
        *(uint4*)(Wh + e) = v;
    }
}

// Single-pass binning. Cursor cell = cur[cell*16] (one 64B line per cell);
// gbin position = cell*CAP + count (closed form).
__global__ __launch_bounds__(256) void k_bin(const int* __restrict__ row,
                                             const int* __restrict__ col,
                                             int* __restrict__ cur,
                                             unsigned* __restrict__ gbin,
                                             int E, int C) {
    const int x = blockIdx.x & (SL - 1);
    int e0 = blockIdx.x * C, e1 = min(E, e0 + C);
    for (int e = e0 + threadIdx.x; e < e1; e += 256) {
        int c = col[e];
        int cell = (c >> 6) * SL + x;
        int cnt = atomicAdd(&cur[cell << 4], 1);
        gbin[cell * CAP + cnt] = (unsigned)row[e] | ((unsigned)(c & 63) << 16);
    }
}

// One block per bucket: LDS histogram of 64 dsts -> (start,deg,dinv), scatter
// 2B src ids into the bucket's padded csrf window, fused x->bf16*dinv cast.
__global__ __launch_bounds__(256) void k_csr(const unsigned* __restrict__ gbin,
                                             const int* __restrict__ cur,
                                             int* __restrict__ rs,
                                             unsigned short* __restrict__ rd,
                                             float* __restrict__ dinv,
                                             unsigned short* __restrict__ csrf,
                                             const float* __restrict__ x,
                                             unsigned short* __restrict__ xb,
                                             int N) {
    const int b = blockIdx.x, t = threadIdx.x;
    __shared__ int hcnt[64], lcur[64], fills[SL];
    __shared__ float sdinv[64];
    if (t < 64) hcnt[t] = 0;
    if (t < SL) fills[t] = cur[(b * SL + t) << 4];
    __syncthreads();
    #pragma unroll 4
    for (int xx = 0; xx < SL; ++xx) {
        int cbase = (b * SL + xx) * CAP, fill = fills[xx];
        for (int i = t; i < fill; i += 256)
            atomicAdd(&hcnt[(gbin[cbase + i] >> 16) & 63], 1);
    }
    __syncthreads();
    if (t < 64) {
        int v = hcnt[t], xs = v;
        #pragma unroll
        for (int off = 1; off < 64; off <<= 1) {
            int u = __shfl_up(xs, off, 64);
            if (t >= off) xs += u;
        }
        int excl = xs - v;
        lcur[t] = excl;
        float d = rsqrtf((float)v + 1.0f);
        sdinv[t] = d;
        int node = b * 64 + t;          // rs/rd/dinv sized NBK*64: always safe
        rs[node] = b * WCAP + excl;
        rd[node] = (unsigned short)v;
        dinv[node] = d;
    }
    __syncthreads();
    #pragma unroll 4
    for (int xx = 0; xx < SL; ++xx) {
        int cbase = (b * SL + xx) * CAP, fill = fills[xx];
        for (int i = t; i < fill; i += 256) {
            unsigned v = gbin[cbase + i];
            int p = atomicAdd(&lcur[(v >> 16) & 63], 1);
            csrf[b * WCAP + p] = (unsigned short)(v & 0xFFFFu);
        }
    }
    // fused x -> bf16*dinv cast (64 nodes x 16 chunks)
    const int node0 = b * 64;
    #pragma unroll
    for (int it = 0; it < 4; ++it) {
        int i = t + it * 256;              // 0..1023
        int nd = node0 + (i >> 4);
        if (nd < N) {
            int ch = i & 15;
            float d = sdinv[i >> 4];
            const float4* s = (const float4*)(x + (size_t)nd * 128 + ch * 8);
            float4 a = s[0], bb = s[1];
            uint4 o;
            o.x = ((unsigned)f2bf(d * a.y) << 16) | f2bf(d * a.x);
            o.y = ((unsigned)f2bf(d * a.w) << 16) | f2bf(d * a.z);
            o.z = ((unsigned)f2bf(d * bb.y) << 16) | f2bf(d * bb.x);
            o.w = ((unsigned)f2bf(d * bb.w) << 16) | f2bf(d * bb.z);
            *(uint4*)(xb + (size_t)nd * 128 + ch * 8) = o;
        }
    }
}

// y[n] = dinv[n] * (sum_src h'[src] + h'[n])   (h', y bf16)
// One wave per node, 4/block: max latency-hiding parallelism for the gather.
__global__ __launch_bounds__(256) void k_agg(const unsigned short* __restrict__ h,
                                             unsigned short* __restrict__ y,
                                             const float* __restrict__ dinv,
                                             const int* __restrict__ rs,
                                             const unsigned short* __restrict__ rd,
                                             const unsigned short* __restrict__ csrf,
                                             int N) {
    const int lane = threadIdx.x & 63;
    const int n = blockIdx.x * 4 + (threadIdx.x >> 6);
    if (n >= N) return;
    const int fg = lane & 15;
    const int slot = lane >> 4;
    const int s = rs[n], e = s + rd[n];

    float acc[8] = {0.f, 0.f, 0.f, 0.f, 0.f, 0.f, 0.f, 0.f};
    for (int base = s; base < e; base += 16) {
        int src_l = csrf[base + fg];               // padded window: in-bounds
        #pragma unroll
        for (int i = 0; i < 4; ++i) {
            int j = i * 4 + slot;
            int src = __shfl(src_l, j, 16);
            uint4 v = *(const uint4*)(h + (size_t)src * 128 + fg * 8);
            bool ok = (base + j) < e;              // mask value, not address
            v.x = ok ? v.x : 0u; v.y = ok ? v.y : 0u;
            v.z = ok ? v.z : 0u; v.w = ok ? v.w : 0u;
            acc[0] += bflo(v.x); acc[1] += bfhi(v.x);
            acc[2] += bflo(v.y); acc[3] += bfhi(v.y);
            acc[4] += bflo(v.z); acc[5] += bfhi(v.z);
            acc[6] += bflo(v.w); acc[7] += bfhi(v.w);
        }
    }
    #pragma unroll
    for (int r = 0; r < 8; ++r) {
        acc[r] += __shfl_xor(acc[r], 16, 64);
        acc[r] += __shfl_xor(acc[r], 32, 64);
    }
    if (slot == 0) {
        float dn = dinv[n];
        uint4 hv = *(const uint4*)(h + (size_t)n * 128 + fg * 8);
        float sv[8] = {bflo(hv.x), bfhi(hv.x), bflo(hv.y), bfhi(hv.y),
                       bflo(hv.z), bfhi(hv.z), bflo(hv.w), bfhi(hv.w)};
        unsigned short ob[8];
        #pragma unroll
        for (int r = 0; r < 8; ++r) ob[r] = f2bf(dn * (acc[r] + sv[r]));
        uint4 o;
        o.x = ((unsigned)ob[1] << 16) | ob[0];
        o.y = ((unsigned)ob[3] << 16) | ob[2];
        o.z = ((unsigned)ob[5] << 16) | ob[4];
        o.w = ((unsigned)ob[7] << 16) | ob[6];
        *(uint4*)(y + (size_t)n * 128 + fg * 8) = o;
    }
}

// C[N,128] = relu(A @ W^T + b) [* dscale[row] if dscale] in bf16 via MFMA.
__global__ __launch_bounds__(256) void k_mm(const unsigned short* __restrict__ A,
                                            const uint4* __restrict__ Wb,
                                            const float* __restrict__ bias,
                                            const float* __restrict__ dscale,
                                            unsigned short* __restrict__ C, int N) {
    __shared__ uint4 Wsh[2048];   // 32 KB, swizzled [o][c^(o&15)]
    const int tid = threadIdx.x;
    #pragma unroll
    for (int it = 0; it < 8; ++it)
        Wsh[tid + it * 256] = Wb[tid + it * 256];

    const int lane = tid & 63;
    const int wv = tid >> 6;
    const int l15 = lane & 15, quad = lane >> 4;
    const int arow_i = blockIdx.x * 64 + wv * 16 + l15;
    const unsigned short* arow = A + (size_t)min(arow_i, N - 1) * 128;

    f32x4 acc[8];
    #pragma unroll
    for (int ct = 0; ct < 8; ++ct) acc[ct] = (f32x4){0.f, 0.f, 0.f, 0.f};

    __syncthreads();
    #pragma unroll
    for (int kiter = 0; kiter < 4; ++kiter) {
        short8 af = *(const short8*)(arow + kiter * 32 + quad * 8);
        const int cswz = (kiter * 4 + quad) ^ l15;
        #pragma unroll
        for (int ct = 0; ct < 8; ++ct) {
            short8 bf = *(const short8*)(&Wsh[((ct * 16 + l15) << 4) | cswz]);
            acc[ct] = __builtin_amdgcn_mfma_f32_16x16x32_bf16(af, bf, acc[ct], 0, 0, 0);
        }
    }

    const int rbase = blockIdx.x * 64 + wv * 16 + quad * 4;
    float ds[4];
    #pragma unroll
    for (int r = 0; r < 4; ++r) {
        int rr = rbase + r;
        ds[r] = (dscale && rr < N) ? dscale[rr] : 1.f;
    }
    #pragma unroll
    for (int ct = 0; ct < 8; ++ct) {
        int colc = ct * 16 + l15;
        float bcol = bias[colc];
        #pragma unroll
        for (int r = 0; r < 4; ++r) {
            int rr = rbase + r;
            if (rr < N) {
                float v = fmaxf(acc[ct][r] + bcol, 0.f) * ds[r];
                C[(size_t)rr * 128 + colc] = f2bf(v);
            }
        }
    }
}

// Mean-pool accumulate (batch sorted), bf16 input, fp32 atomics out.
__global__ __launch_bounds__(256) void k_pool(const unsigned short* __restrict__ h,
                                              const int* __restrict__ batch,
                                              float* __restrict__ pool,
                                              float* __restrict__ cnt, int N) {
    int t = threadIdx.x;
    int fg = t & 15, sg = t >> 4;
    int n0 = blockIdx.x * 512 + sg * 32;
    if (n0 >= N) return;
    int n1 = min(n0 + 32, N);
    int gprev = batch[n0];
    float racc[8] = {0.f, 0.f, 0.f, 0.f, 0.f, 0.f, 0.f, 0.f};
    float rcnt = 0.f;
    for (int n = n0; n < n1; ++n) {
        int g = batch[n];
        if (g != gprev) {
            float* dst = pool + (size_t)gprev * 128 + fg * 8;
            #pragma unroll
            for (int r = 0; r < 8; ++r) atomicAdd(dst + r, racc[r]);
            if (fg == 0) atomicAdd(&cnt[gprev], rcnt);
            #pragma unroll
            for (int r = 0; r < 8; ++r) racc[r] = 0.f;
            rcnt = 0.f; gprev = g;
        }
        uint4 v = *(const uint4*)(h + (size_t)n * 128 + fg * 8);
        racc[0] += bflo(v.x); racc[1] += bfhi(v.x);
        racc[2] += bflo(v.y); racc[3] += bfhi(v.y);
        racc[4] += bflo(v.z); racc[5] += bfhi(v.z);
        racc[6] += bflo(v.w); racc[7] += bfhi(v.w);
        rcnt += 1.f;
    }
    float* dst = pool + (size_t)gprev * 128 + fg * 8;
    #pragma unroll
    for (int r = 0; r < 8; ++r) atomicAdd(dst + r, racc[r]);
    if (fg == 0) atomicAdd(&cnt[gprev], rcnt);
}

// Fused head via MFMA: 16 graphs/block (M=16), 256 thr = 4 waves. Activations
// bf16 in LDS; B-frags from bf16 weight arena in global (L2-hot). Each wave
// owns 4 of 16 output-tiles per 256-out layer. fp32 accumulation throughout.
__global__ __launch_bounds__(256) void k_head(
    const unsigned short* __restrict__ Wh,
    const float* __restrict__ pool, const float* __restrict__ cnt,
    const float* __restrict__ mol,
    const float* __restrict__ mlpb, const float* __restrict__ mlob,
    const float* __restrict__ gcnob,
    const float* __restrict__ pb1, const float* __restrict__ pb2,
    const float* __restrict__ oW, const float* __restrict__ ob,
    float* __restrict__ out, int G) {
    const int g0 = blockIdx.x * 16;
    const int t = threadIdx.x;
    const int lane = t & 63, wv = t >> 6;
    const int l15 = lane & 15, quad = lane >> 4;
    __shared__ unsigned short A[16][264], B[16][264], Cc[16][200], Mn[16][136];
    __shared__ float red[4][16];

    for (int i = t; i < 16 * 256; i += 256) {
        int g = i >> 8, k = i & 255;
        A[g][k] = f2bf(mol[(size_t)(g0 + g) * 256 + k]);
    }
    for (int i = t; i < 16 * 128; i += 256) {
        int g = i >> 7, k = i & 127;
        float c = cnt[g0 + g];
        Mn[g][k] = f2bf(pool[(size_t)(g0 + g) * 128 + k] / fmaxf(c, 1.f));
    }
    __syncthreads();

    // one 16x16 output tile: rows=graphs, cols=ocol..ocol+15 (lane col=l15)
    auto do_tile = [&](const unsigned short* actb, int astr, int K,
                       const unsigned short* W, int orow,
                       const float* __restrict__ bias, int bidx,
                       unsigned short* dstb, int dstr, int ocol, bool dorelu) {
        f32x4 c = {0.f, 0.f, 0.f, 0.f};
        for (int kt = 0; kt < (K >> 5); ++kt) {
            short8 af = *(const short8*)(actb + (size_t)l15 * astr + kt * 32 + quad * 8);
            short8 bf = *(const short8*)(W + (size_t)orow * K + kt * 32 + quad * 8);
            c = __builtin_amdgcn_mfma_f32_16x16x32_bf16(af, bf, c, 0, 0, 0);
        }
        float bb = bias[bidx];
        #pragma unroll
        for (int r = 0; r < 4; ++r) {
            int g = quad * 4 + r;
            float v = c[r] + bb;
            if (dorelu) v = fmaxf(v, 0.f);
            dstb[(size_t)g * dstr + ocol] = f2bf(v);
        }
    };

    // mlp0: A(K=256) -> B relu
    #pragma unroll
    for (int nt = 0; nt < 4; ++nt) {
        int o = (wv * 4 + nt) * 16 + l15;
        do_tile(&A[0][0], 264, 256, Wh + HW_MLP0, o, mlpb, o, &B[0][0], 264, o, true);
    }
    __syncthreads();
    // mlp1: B(K=256) -> A relu
    #pragma unroll
    for (int nt = 0; nt < 4; ++nt) {
        int o = (wv * 4 + nt) * 16 + l15;
        do_tile(&B[0][0], 264, 256, Wh + HW_MLP1, o, mlpb + 256, o, &A[0][0], 264, o, true);
    }
    __syncthreads();
    // concat -> Cc[16][192]: tiles 0..7 gcn_out (K=128 from Mn, no relu),
    // tiles 8..11 mlo (K=256 from A, relu, cols 128..191). Wave w: tiles 3w..3w+2.
    #pragma unroll
    for (int j = 0; j < 3; ++j) {
        int tile = wv * 3 + j;
        if (tile < 8) {
            int o = tile * 16 + l15;
            do_tile(&Mn[0][0], 136, 128, Wh + HW_GCNO, o, gcnob, o, &Cc[0][0], 200, o, false);
        } else {
            int om = (tile - 8) * 16 + l15;
            do_tile(&A[0][0], 264, 256, Wh + HW_MLO, om, mlob, om, &Cc[0][0], 200, 128 + om, true);
        }
    }
    __syncthreads();
    // pred1: Cc(K=192) -> B relu
    #pragma unroll
    for (int nt = 0; nt < 4; ++nt) {
        int o = (wv * 4 + nt) * 16 + l15;
        do_tile(&Cc[0][0], 200, 192, Wh + HW_PW1, o, pb1, o, &B[0][0], 264, o, true);
    }
    __syncthreads();
    // pred2 (K=256) fused with out-dot
    {
        float pacc[4] = {0.f, 0.f, 0.f, 0.f};
        #pragma unroll
        for (int nt = 0; nt < 4; ++nt) {
            int o = (wv * 4 + nt) * 16 + l15;
            f32x4 c = {0.f, 0.f, 0.f, 0.f};
            #pragma unroll
            for (int kt = 0; kt < 8; ++kt) {
                short8 af = *(const short8*)(&B[0][0] + (size_t)l15 * 264 + kt * 32 + quad * 8);
                short8 bf = *(const short8*)(Wh + HW_PW2 + (size_t)o * 256 + kt * 32 + quad * 8);
                c = __builtin_amdgcn_mfma_f32_16x16x32_bf16(af, bf, c, 0, 0, 0);
            }
            float bb = pb2[o], wo = oW[o];
            #pragma unroll
            for (int r = 0; r < 4; ++r)
                pacc[r] += fmaxf(c[r] + bb, 0.f) * wo;
        }
        // reduce over l15 (16 lanes within quad)
        #pragma unroll
        for (int off = 1; off < 16; off <<= 1)
            #pragma unroll
            for (int r = 0; r < 4; ++r)
                pacc[r] += __shfl_xor(pacc[r], off, 64);
        if (l15 == 0) {
            #pragma unroll
            for (int r = 0; r < 4; ++r)
                red[wv][quad * 4 + r] = pacc[r];
        }
    }
    __syncthreads();
    if (t < 16) {
        float s = red[0][t] + red[1][t] + red[2][t] + red[3][t] + ob[0];
        if (g0 + t < G) out[g0 + t] = s;
    }
}

extern "C" void kernel_launch(void* const* d_in, const int* in_sizes, int n_in,
                              void* d_out, int out_size, void* d_ws, size_t ws_size,
                              hipStream_t stream) {
    const float* x     = (const float*)d_in[0];
    const int*   ei    = (const int*)d_in[1];
    const int*   batch = (const int*)d_in[2];
    const float* mol   = (const float*)d_in[3];
    const float* gcnW  = (const float*)d_in[4];
    const float* gcnb  = (const float*)d_in[5];
    const float* gcnoW = (const float*)d_in[6];
    const float* gcnob = (const float*)d_in[7];
    const float* mlpW  = (const float*)d_in[8];
    const float* mlpb  = (const float*)d_in[9];
    const float* mloW  = (const float*)d_in[10];
    const float* mlob  = (const float*)d_in[11];
    const float* pW1   = (const float*)d_in[12];
    const float* pb1   = (const float*)d_in[13];
    const float* pW2   = (const float*)d_in[14];
    const float* pb2   = (const float*)d_in[15];
    const float* oW    = (const float*)d_in[16];
    const float* ob    = (const float*)d_in[17];

    const int N = in_sizes[0] / 128;
    const int E = in_sizes[1] / 2;
    const int G = in_sizes[3] / 256;
    const int* row = ei;
    const int* col = ei + E;

    const int NBK = (N + BKT - 1) / BKT;       // 782 buckets
    const int M = NBK * SL;                    // 12512 cells
    const int C = (E + NBINBLK - 1) / NBINBLK; // edges per bin block

    char* p = (char*)d_ws;
    auto alloc = [&](size_t bytes) {
        char* q = p;
        p += (bytes + 255) & ~(size_t)255;
        return (void*)q;
    };
    int*    rs    = (int*)alloc((size_t)NBK * 64 * 4);
    unsigned short* rd = (unsigned short*)alloc((size_t)NBK * 64 * 2);
    float*  dinv  = (float*)alloc((size_t)NBK * 64 * 4);
    int*    cur   = (int*)alloc((size_t)M * 16 * 4);   // line-padded cursors
    unsigned* gbin = (unsigned*)alloc((size_t)M * CAP * 4);
    unsigned short* csrf = (unsigned short*)alloc(((size_t)NBK * WCAP + 32) * 2);
    unsigned short* xb   = (unsigned short*)alloc((size_t)HROWS * 128 * 2);
    unsigned short* bufA = (unsigned short*)alloc((size_t)HROWS * 128 * 2);
    unsigned short* bufB = (unsigned short*)alloc((size_t)HROWS * 128 * 2);
    uint4*  Wb    = (uint4*)alloc((size_t)3 * 2048 * 16);
    unsigned short* Wh = (unsigned short*)alloc((size_t)HW_TOT * 2);
    float*  pool  = (float*)alloc((size_t)G * 128 * 4);
    float*  cnt   = (float*)alloc((size_t)G * 4);

    const int initblocks = (M * 16 + 255) / 256;   // covers cursors + casts

    k_init<<<initblocks, 256, 0, stream>>>(cur, pool, cnt, gcnW, Wb,
                                           mlpW, mloW, gcnoW, pW1, pW2, Wh, M, G);
    k_bin<<<NBINBLK, 256, 0, stream>>>(row, col, cur, gbin, E, C);
    k_csr<<<NBK, 256, 0, stream>>>(gbin, cur, rs, rd, dinv, csrf, x, xb, N);

    const int mmblocks = (N + 63) / 64;
    const int aggblocks = (N + 3) / 4;
    const unsigned short* src = xb;
    for (int l = 0; l < 3; ++l) {
        k_agg<<<aggblocks, 256, 0, stream>>>(src, bufA, dinv, rs, rd, csrf, N);
        k_mm<<<mmblocks, 256, 0, stream>>>(bufA, Wb + (size_t)l * 2048,
                                           gcnb + (size_t)l * 128,
                                           (l < 2) ? dinv : (const float*)nullptr,
                                           bufB, N);
        src = bufB;
    }
    k_pool<<<(N + 511) / 512, 256, 0, stream>>>(bufB, batch, pool, cnt, N);
    k_head<<<(G + 15) / 16, 256, 0, stream>>>(
        Wh, pool, cnt, mol, mlpb, mlob, gcnob, pb1, pb2, oW, ob,
        (float*)d_out, G);
}